// Round 1
// baseline (147.430 us; speedup 1.0000x reference)
//
#include <hip/hip_runtime.h>
#include <math.h>

// ---------------------------------------------------------------------------
// StageALoss (FCOS-like): conf focal loss over all locations, CIoU over
// in-box locations, quality BCE at the argmin-dist location per (level,batch).
//
// Insight: in_box / dist2 / argmin depend only on gt_bboxes + grid coords.
//  - qual maps: only 4 gathered floats per (level,batch) -> never streamed.
//  - det ch1..4: only needed where in_box -> wave-uniform skip via __any.
//  - invalid batches (b%16==0): contribute 0 to everything -> block early-out.
// ---------------------------------------------------------------------------

#define N_PB 384  // 3 levels * 128 batches

__device__ __forceinline__ float logsigf(float x) {
    // log(sigmoid(x)) = min(x,0) - log1p(exp(-|x|))
    return fminf(x, 0.f) - log1pf(expf(-fabsf(x)));
}

__global__ __launch_bounds__(512) void init_ws_k(unsigned long long* __restrict__ packed,
                                                 float* __restrict__ ciou,
                                                 int* __restrict__ npos,
                                                 float* __restrict__ conf) {
    int i = threadIdx.x;
    if (i < N_PB) { packed[i] = ~0ULL; ciou[i] = 0.f; npos[i] = 0; }
    if (i == N_PB) conf[0] = 0.f;
}

// Flat vec-index space (each vec = 4 consecutive x locations):
//   lvl0: 128 * 16384/4 = 524288 vecs (4096/batch)
//   lvl1: 128 *  4096/4 = 131072 vecs (1024/batch)
//   lvl2: 128 *  1024/4 =  32768 vecs ( 256/batch)
// total 688128 vecs = 2688 blocks * 256 threads, blocks never span a batch.
__global__ __launch_bounds__(256) void level_k(
    const float* __restrict__ det8, const float* __restrict__ det16, const float* __restrict__ det32,
    const float* __restrict__ gtb,
    unsigned long long* __restrict__ packed_ws, float* __restrict__ ciou_ws,
    int* __restrict__ npos_ws, float* __restrict__ conf_ws)
{
    const int flat0 = blockIdx.x << 8;  // block-uniform
    int lvl, b, locv0, log2W, log2HW;
    const float* det; float stride; float inv_denom;
    if (flat0 < 524288) {
        lvl = 0; b = flat0 >> 12; locv0 = flat0 & 4095;
        det = det8;  stride = 8.f;  log2W = 7; log2HW = 14; inv_denom = 1.f / 2097152.f;
    } else if (flat0 < 655360) {
        int v = flat0 - 524288;
        lvl = 1; b = v >> 10; locv0 = v & 1023;
        det = det16; stride = 16.f; log2W = 6; log2HW = 12; inv_denom = 1.f / 524288.f;
    } else {
        int v = flat0 - 655360;
        lvl = 2; b = v >> 8; locv0 = v & 255;
        det = det32; stride = 32.f; log2W = 5; log2HW = 10; inv_denom = 1.f / 131072.f;
    }

    const float x1 = gtb[b * 4 + 0];
    if (x1 < 0.f) return;  // invalid batch: contributes exactly 0 everywhere
    const float y1 = gtb[b * 4 + 1];
    const float x2 = gtb[b * 4 + 2];
    const float y2 = gtb[b * 4 + 3];
    const float bcx = 0.5f * (x1 + x2);
    const float bcy = 0.5f * (y1 + y2);

    const int locv = locv0 + (int)threadIdx.x;
    const int loc  = locv << 2;                 // element index in [0, H*W)
    const int W    = 1 << log2W;
    const int xi   = loc & (W - 1);
    const int yi   = loc >> log2W;
    const float cy = ((float)yi + 0.5f) * stride;
    const size_t HW   = (size_t)1 << log2HW;
    const size_t base = ((size_t)(b * 5) << log2HW) + (size_t)loc;

    // in_box depends only on coords -> decide before loading ltrb channels
    float cxs[4]; bool inb[4]; bool anyb = false;
    #pragma unroll
    for (int j = 0; j < 4; ++j) {
        cxs[j] = ((float)(xi + j) + 0.5f) * stride;
        inb[j] = (cxs[j] > x1) & (cxs[j] < x2) & (cy > y1) & (cy < y2);
        anyb |= inb[j];
    }

    // channel 0: confidence focal loss for every location
    const float4 d0 = *(const float4*)(det + base);
    const float zs[4] = { d0.x, d0.y, d0.z, d0.w };
    float conf_loc = 0.f;
    #pragma unroll
    for (int j = 0; j < 4; ++j) {
        const float z  = zs[j];
        const float t  = inb[j] ? 1.f : 0.f;
        const float ce = fmaxf(z, 0.f) - z * t + log1pf(expf(-fabsf(z)));
        const float p  = 1.f / (1.f + expf(-z));
        const float pt = inb[j] ? p : 1.f - p;
        const float at = inb[j] ? 0.25f : 0.75f;
        const float om = 1.f - pt;
        conf_loc += at * om * om * ce;
    }
    conf_loc *= inv_denom;  // pre-divide by B*H*W of this level

    float ciou_loc = 0.f;
    int   np_loc   = 0;
    unsigned long long pk = ~0ULL;

    if (__any(anyb)) {  // wave-uniform: load ltrb channels only near boxes
        const float4 d1 = *(const float4*)(det + base + HW);
        const float4 d2 = *(const float4*)(det + base + 2 * HW);
        const float4 d3 = *(const float4*)(det + base + 3 * HW);
        const float4 d4 = *(const float4*)(det + base + 4 * HW);
        const float ls[4] = { d1.x, d1.y, d1.z, d1.w };
        const float ts[4] = { d2.x, d2.y, d2.z, d2.w };
        const float rs[4] = { d3.x, d3.y, d3.z, d3.w };
        const float bs[4] = { d4.x, d4.y, d4.z, d4.w };
        #pragma unroll
        for (int j = 0; j < 4; ++j) {
            if (!inb[j]) continue;
            const float cx = cxs[j];
            const float pl  = expf(fminf(fmaxf(ls[j], -6.f), 6.f)) * stride;
            const float pt_ = expf(fminf(fmaxf(ts[j], -6.f), 6.f)) * stride;
            const float pr  = expf(fminf(fmaxf(rs[j], -6.f), 6.f)) * stride;
            const float pb  = expf(fminf(fmaxf(bs[j], -6.f), 6.f)) * stride;
            const float gl  = cx - x1, gtl = cy - y1, gr = x2 - cx, gb = y2 - cy;
            const float pw = pl + pr, ph = pt_ + pb;
            const float gw = gl + gr, gh = gtl + gb;
            const float iw = fmaxf(fminf(pl, gl) + fminf(pr, gr), 0.f);
            const float ih = fmaxf(fminf(pt_, gtl) + fminf(pb, gb), 0.f);
            const float inter = iw * ih;
            const float uni   = pw * ph + gw * gh - inter + 1e-6f;
            const float iou   = inter / uni;
            const float cw_ = fmaxf(pl, gl) + fmaxf(pr, gr);
            const float ch_ = fmaxf(pt_, gtl) + fmaxf(pb, gb);
            const float c2  = cw_ * cw_ + ch_ * ch_ + 1e-6f;
            const float dcx = 0.5f * (pr - pl) - 0.5f * (gr - gl);
            const float dcy = 0.5f * (pb - pt_) - 0.5f * (gb - gtl);
            const float rho2 = dcx * dcx + dcy * dcy;
            const float dv = atanf(gw / (gh + 1e-6f)) - atanf(pw / (ph + 1e-6f));
            const float v  = (4.f / (float)(M_PI * M_PI)) * dv * dv;
            const float alpha = v / (1.f - iou + v + 1e-6f);
            ciou_loc += 1.f - iou + rho2 / c2 + alpha * v;
            ++np_loc;
            const float ddx = cx - bcx, ddy = cy - bcy;
            const float dist2 = ddx * ddx + ddy * ddy;
            const unsigned long long cand =
                ((unsigned long long)__float_as_uint(dist2) << 32) | (unsigned)(loc + j);
            pk = cand < pk ? cand : pk;  // min -> first-index tie-break like argmin
        }
    }

    // wave-level (64-lane) reduction, then one atomic per wave per quantity
    #pragma unroll
    for (int off = 32; off > 0; off >>= 1) {
        conf_loc += __shfl_down(conf_loc, off);
        ciou_loc += __shfl_down(ciou_loc, off);
        np_loc   += __shfl_down(np_loc, off);
        unsigned long long o = __shfl_down(pk, off);
        pk = o < pk ? o : pk;
    }
    if ((threadIdx.x & 63) == 0) {
        atomicAdd(conf_ws, conf_loc);
        if (np_loc > 0) {
            const int slot = lvl * 128 + b;
            atomicAdd(&ciou_ws[slot], ciou_loc);
            atomicAdd(&npos_ws[slot], np_loc);
            atomicMin(&packed_ws[slot], pk);
        }
    }
}

__global__ __launch_bounds__(512) void fin_k(
    const float* __restrict__ q8, const float* __restrict__ q16, const float* __restrict__ q32,
    const float* __restrict__ gtq,
    const unsigned long long* __restrict__ packed_ws, const float* __restrict__ ciou_ws,
    const int* __restrict__ npos_ws, const float* __restrict__ conf_ws,
    float* __restrict__ out)
{
    __shared__ float sb[512];
    __shared__ float sq[512];
    __shared__ int   sn[512];
    const int i = threadIdx.x;
    float bb = 0.f, ql = 0.f; int n = 0;
    if (i < N_PB) {
        const int np = npos_ws[i];
        if (np > 0) {
            const int lvl = i >> 7, b = i & 127;
            bb = ciou_ws[i] / (float)np;  // ciou_mean (npos>=1)
            const unsigned idx = (unsigned)(packed_ws[i] & 0xffffffffULL);
            const float* q; int log2HW;
            if (lvl == 0)      { q = q8;  log2HW = 14; }
            else if (lvl == 1) { q = q16; log2HW = 12; }
            else               { q = q32; log2HW = 10; }
            float s = 0.f;
            #pragma unroll
            for (int c = 0; c < 4; ++c) {
                const float best = q[((size_t)(b * 4 + c) << log2HW) + idx];
                const float qt = fminf(fmaxf(gtq[b * 4 + c], 0.05f), 0.95f);
                s -= qt * logsigf(best) + (1.f - qt) * logsigf(-best);
            }
            ql = 0.25f * s;  // bce.mean over C_Q=4
            n = 1;           // has_pos
        }
    }
    sb[i] = bb; sq[i] = ql; sn[i] = n;
    __syncthreads();
    #pragma unroll
    for (int off = 256; off > 0; off >>= 1) {
        if (i < off) { sb[i] += sb[i + off]; sq[i] += sq[i + off]; sn[i] += sn[i + off]; }
        __syncthreads();
    }
    if (i == 0) {
        const float conf = conf_ws[0];
        const int ntot = sn[0];
        const float denom = fmaxf((float)ntot, 1.f);
        const float tb = (ntot > 0) ? sb[0] / denom : sb[0];
        const float tq = (ntot > 0) ? sq[0] / denom : sq[0];
        out[0] = conf + 5.f * tb + 0.05f * tq;
        out[1] = conf;
        out[2] = tb;
        out[3] = tq;
    }
}

extern "C" void kernel_launch(void* const* d_in, const int* in_sizes, int n_in,
                              void* d_out, int out_size, void* d_ws, size_t ws_size,
                              hipStream_t stream) {
    const float* det8  = (const float*)d_in[0];
    const float* det16 = (const float*)d_in[1];
    const float* det32 = (const float*)d_in[2];
    const float* q8    = (const float*)d_in[3];
    const float* q16   = (const float*)d_in[4];
    const float* q32   = (const float*)d_in[5];
    const float* gtb   = (const float*)d_in[6];
    const float* gtq   = (const float*)d_in[7];
    float* out = (float*)d_out;

    // workspace layout (<= 6148 bytes)
    unsigned long long* packed = (unsigned long long*)d_ws;                 // 384 * 8
    float* ciou_ws = (float*)((char*)d_ws + 3072);                          // 384 * 4
    int*   npos_ws = (int*)((char*)d_ws + 4608);                            // 384 * 4
    float* conf_ws = (float*)((char*)d_ws + 6144);                          // 1 * 4

    hipLaunchKernelGGL(init_ws_k, dim3(1), dim3(512), 0, stream,
                       packed, ciou_ws, npos_ws, conf_ws);
    hipLaunchKernelGGL(level_k, dim3(2688), dim3(256), 0, stream,
                       det8, det16, det32, gtb, packed, ciou_ws, npos_ws, conf_ws);
    hipLaunchKernelGGL(fin_k, dim3(1), dim3(512), 0, stream,
                       q8, q16, q32, gtq, packed, ciou_ws, npos_ws, conf_ws, out);
}

// Round 2
// 36.790 us; speedup vs baseline: 4.0073x; 4.0073x over previous
//
#include <hip/hip_runtime.h>
#include <math.h>

// ---------------------------------------------------------------------------
// StageALoss (FCOS-like): conf focal loss over all locations, CIoU over
// in-box locations, quality BCE at the argmin-dist location per (level,batch).
//
// R1 -> R2: level_k was stall-bound (138us, VALUBusy 10%, HBM 0.9%) on
// 10752 same-address atomicAdd(conf_ws). Replaced with block-LDS reduction +
// contention-free per-block partial stores; slot atomics cut 4x (per-block,
// not per-wave). One expf instead of two in the focal term.
// ---------------------------------------------------------------------------

#define N_PB 384  // 3 levels * 128 batches
#define N_BLK 2688

__device__ __forceinline__ float logsigf(float x) {
    return fminf(x, 0.f) - log1pf(expf(-fabsf(x)));
}

__global__ __launch_bounds__(512) void init_ws_k(unsigned long long* __restrict__ packed,
                                                 float* __restrict__ ciou,
                                                 int* __restrict__ npos) {
    int i = threadIdx.x;
    if (i < N_PB) { packed[i] = ~0ULL; ciou[i] = 0.f; npos[i] = 0; }
}

// Flat vec-index space (each vec = 4 consecutive x locations):
//   lvl0: 128 * 16384/4 = 524288 vecs (4096/batch, 16 blocks/batch)
//   lvl1: 128 *  4096/4 = 131072 vecs (1024/batch,  4 blocks/batch)
//   lvl2: 128 *  1024/4 =  32768 vecs ( 256/batch,  1 block /batch)
// total 688128 vecs = 2688 blocks * 256 threads; blocks never span a batch,
// so (lvl, b) — and the ws slot — are block-uniform.
__global__ __launch_bounds__(256) void level_k(
    const float* __restrict__ det8, const float* __restrict__ det16, const float* __restrict__ det32,
    const float* __restrict__ gtb,
    float* __restrict__ conf_part,
    unsigned long long* __restrict__ packed_ws, float* __restrict__ ciou_ws,
    int* __restrict__ npos_ws)
{
    const int flat0 = blockIdx.x << 8;  // block-uniform
    int lvl, b, locv0, log2W, log2HW;
    const float* det; float stride; float inv_denom;
    if (flat0 < 524288) {
        lvl = 0; b = flat0 >> 12; locv0 = flat0 & 4095;
        det = det8;  stride = 8.f;  log2W = 7; log2HW = 14; inv_denom = 1.f / 2097152.f;
    } else if (flat0 < 655360) {
        int v = flat0 - 524288;
        lvl = 1; b = v >> 10; locv0 = v & 1023;
        det = det16; stride = 16.f; log2W = 6; log2HW = 12; inv_denom = 1.f / 524288.f;
    } else {
        int v = flat0 - 655360;
        lvl = 2; b = v >> 8; locv0 = v & 255;
        det = det32; stride = 32.f; log2W = 5; log2HW = 10; inv_denom = 1.f / 131072.f;
    }

    const float x1 = gtb[b * 4 + 0];
    if (x1 < 0.f) {  // invalid batch: contributes exactly 0 everywhere
        if (threadIdx.x == 0) conf_part[blockIdx.x] = 0.f;
        return;
    }
    const float y1 = gtb[b * 4 + 1];
    const float x2 = gtb[b * 4 + 2];
    const float y2 = gtb[b * 4 + 3];
    const float bcx = 0.5f * (x1 + x2);
    const float bcy = 0.5f * (y1 + y2);

    const int locv = locv0 + (int)threadIdx.x;
    const int loc  = locv << 2;                 // element index in [0, H*W)
    const int W    = 1 << log2W;
    const int xi   = loc & (W - 1);
    const int yi   = loc >> log2W;
    const float cy = ((float)yi + 0.5f) * stride;
    const size_t HW   = (size_t)1 << log2HW;
    const size_t base = ((size_t)(b * 5) << log2HW) + (size_t)loc;

    // in_box depends only on coords -> decide before loading ltrb channels
    float cxs[4]; bool inb[4]; bool anyb = false;
    #pragma unroll
    for (int j = 0; j < 4; ++j) {
        cxs[j] = ((float)(xi + j) + 0.5f) * stride;
        inb[j] = (cxs[j] > x1) & (cxs[j] < x2) & (cy > y1) & (cy < y2);
        anyb |= inb[j];
    }

    // channel 0: confidence focal loss for every location (one expf per loc)
    const float4 d0 = *(const float4*)(det + base);
    const float zs[4] = { d0.x, d0.y, d0.z, d0.w };
    float conf_loc = 0.f;
    #pragma unroll
    for (int j = 0; j < 4; ++j) {
        const float z  = zs[j];
        const float t  = inb[j] ? 1.f : 0.f;
        const float e  = expf(-fabsf(z));          // in (0, 1]
        const float ce = fmaxf(z, 0.f) - z * t + log1pf(e);
        const float inv_den = 1.f / (1.f + e);
        const float p  = (z >= 0.f) ? inv_den : e * inv_den;   // sigmoid(z)
        const float pt = inb[j] ? p : 1.f - p;
        const float at = inb[j] ? 0.25f : 0.75f;
        const float om = 1.f - pt;
        conf_loc += at * om * om * ce;
    }
    conf_loc *= inv_denom;  // pre-divide by B*H*W of this level

    float ciou_loc = 0.f;
    int   np_loc   = 0;
    unsigned long long pk = ~0ULL;

    if (__any(anyb)) {  // wave-uniform: load ltrb channels only near boxes
        const float4 d1 = *(const float4*)(det + base + HW);
        const float4 d2 = *(const float4*)(det + base + 2 * HW);
        const float4 d3 = *(const float4*)(det + base + 3 * HW);
        const float4 d4 = *(const float4*)(det + base + 4 * HW);
        const float ls[4] = { d1.x, d1.y, d1.z, d1.w };
        const float ts[4] = { d2.x, d2.y, d2.z, d2.w };
        const float rs[4] = { d3.x, d3.y, d3.z, d3.w };
        const float bs[4] = { d4.x, d4.y, d4.z, d4.w };
        #pragma unroll
        for (int j = 0; j < 4; ++j) {
            if (!inb[j]) continue;
            const float cx = cxs[j];
            const float pl  = expf(fminf(fmaxf(ls[j], -6.f), 6.f)) * stride;
            const float pt_ = expf(fminf(fmaxf(ts[j], -6.f), 6.f)) * stride;
            const float pr  = expf(fminf(fmaxf(rs[j], -6.f), 6.f)) * stride;
            const float pb  = expf(fminf(fmaxf(bs[j], -6.f), 6.f)) * stride;
            const float gl  = cx - x1, gtl = cy - y1, gr = x2 - cx, gb = y2 - cy;
            const float pw = pl + pr, ph = pt_ + pb;
            const float gw = gl + gr, gh = gtl + gb;
            const float iw = fmaxf(fminf(pl, gl) + fminf(pr, gr), 0.f);
            const float ih = fmaxf(fminf(pt_, gtl) + fminf(pb, gb), 0.f);
            const float inter = iw * ih;
            const float uni   = pw * ph + gw * gh - inter + 1e-6f;
            const float iou   = inter / uni;
            const float cw_ = fmaxf(pl, gl) + fmaxf(pr, gr);
            const float ch_ = fmaxf(pt_, gtl) + fmaxf(pb, gb);
            const float c2  = cw_ * cw_ + ch_ * ch_ + 1e-6f;
            const float dcx = 0.5f * (pr - pl) - 0.5f * (gr - gl);
            const float dcy = 0.5f * (pb - pt_) - 0.5f * (gb - gtl);
            const float rho2 = dcx * dcx + dcy * dcy;
            const float dv = atanf(gw / (gh + 1e-6f)) - atanf(pw / (ph + 1e-6f));
            const float v  = (4.f / (float)(M_PI * M_PI)) * dv * dv;
            const float alpha = v / (1.f - iou + v + 1e-6f);
            ciou_loc += 1.f - iou + rho2 / c2 + alpha * v;
            ++np_loc;
            const float ddx = cx - bcx, ddy = cy - bcy;
            const float dist2 = ddx * ddx + ddy * ddy;
            const unsigned long long cand =
                ((unsigned long long)__float_as_uint(dist2) << 32) | (unsigned)(loc + j);
            pk = cand < pk ? cand : pk;  // min -> first-index tie-break like argmin
        }
    }

    // wave-level (64-lane) shuffle reduction
    #pragma unroll
    for (int off = 32; off > 0; off >>= 1) {
        conf_loc += __shfl_down(conf_loc, off);
        ciou_loc += __shfl_down(ciou_loc, off);
        np_loc   += __shfl_down(np_loc, off);
        unsigned long long o = __shfl_down(pk, off);
        pk = o < pk ? o : pk;
    }

    // block-level reduction across the 4 waves (slot is block-uniform)
    __shared__ float s_conf[4], s_ciou[4];
    __shared__ int   s_np[4];
    __shared__ unsigned long long s_pk[4];
    const int wid = threadIdx.x >> 6;
    if ((threadIdx.x & 63) == 0) {
        s_conf[wid] = conf_loc; s_ciou[wid] = ciou_loc; s_np[wid] = np_loc; s_pk[wid] = pk;
    }
    __syncthreads();
    if (threadIdx.x == 0) {
        float c = s_conf[0] + s_conf[1] + s_conf[2] + s_conf[3];
        conf_part[blockIdx.x] = c;   // contention-free partial store
        float ci = s_ciou[0] + s_ciou[1] + s_ciou[2] + s_ciou[3];
        int   np = s_np[0] + s_np[1] + s_np[2] + s_np[3];
        unsigned long long mn = s_pk[0];
        mn = s_pk[1] < mn ? s_pk[1] : mn;
        mn = s_pk[2] < mn ? s_pk[2] : mn;
        mn = s_pk[3] < mn ? s_pk[3] : mn;
        if (np > 0) {
            const int slot = lvl * 128 + b;
            atomicAdd(&ciou_ws[slot], ci);
            atomicAdd(&npos_ws[slot], np);
            atomicMin(&packed_ws[slot], mn);
        }
    }
}

__global__ __launch_bounds__(512) void fin_k(
    const float* __restrict__ q8, const float* __restrict__ q16, const float* __restrict__ q32,
    const float* __restrict__ gtq,
    const float* __restrict__ conf_part,
    const unsigned long long* __restrict__ packed_ws, const float* __restrict__ ciou_ws,
    const int* __restrict__ npos_ws,
    float* __restrict__ out)
{
    __shared__ float sc[512];
    __shared__ float sb[512];
    __shared__ float sq[512];
    __shared__ int   sn[512];
    const int i = threadIdx.x;

    float cp = 0.f;
    for (int j = i; j < N_BLK; j += 512) cp += conf_part[j];

    float bb = 0.f, ql = 0.f; int n = 0;
    if (i < N_PB) {
        const int np = npos_ws[i];
        if (np > 0) {
            const int lvl = i >> 7, b = i & 127;
            bb = ciou_ws[i] / (float)np;  // ciou_mean (npos>=1)
            const unsigned idx = (unsigned)(packed_ws[i] & 0xffffffffULL);
            const float* q; int log2HW;
            if (lvl == 0)      { q = q8;  log2HW = 14; }
            else if (lvl == 1) { q = q16; log2HW = 12; }
            else               { q = q32; log2HW = 10; }
            float s = 0.f;
            #pragma unroll
            for (int c = 0; c < 4; ++c) {
                const float best = q[((size_t)(b * 4 + c) << log2HW) + idx];
                const float qt = fminf(fmaxf(gtq[b * 4 + c], 0.05f), 0.95f);
                s -= qt * logsigf(best) + (1.f - qt) * logsigf(-best);
            }
            ql = 0.25f * s;  // bce.mean over C_Q=4
            n = 1;           // has_pos
        }
    }
    sc[i] = cp; sb[i] = bb; sq[i] = ql; sn[i] = n;
    __syncthreads();
    #pragma unroll
    for (int off = 256; off > 0; off >>= 1) {
        if (i < off) { sc[i] += sc[i + off]; sb[i] += sb[i + off]; sq[i] += sq[i + off]; sn[i] += sn[i + off]; }
        __syncthreads();
    }
    if (i == 0) {
        const float conf = sc[0];
        const int ntot = sn[0];
        const float denom = fmaxf((float)ntot, 1.f);
        const float tb = (ntot > 0) ? sb[0] / denom : sb[0];
        const float tq = (ntot > 0) ? sq[0] / denom : sq[0];
        out[0] = conf + 5.f * tb + 0.05f * tq;
        out[1] = conf;
        out[2] = tb;
        out[3] = tq;
    }
}

extern "C" void kernel_launch(void* const* d_in, const int* in_sizes, int n_in,
                              void* d_out, int out_size, void* d_ws, size_t ws_size,
                              hipStream_t stream) {
    const float* det8  = (const float*)d_in[0];
    const float* det16 = (const float*)d_in[1];
    const float* det32 = (const float*)d_in[2];
    const float* q8    = (const float*)d_in[3];
    const float* q16   = (const float*)d_in[4];
    const float* q32   = (const float*)d_in[5];
    const float* gtb   = (const float*)d_in[6];
    const float* gtq   = (const float*)d_in[7];
    float* out = (float*)d_out;

    // workspace layout (16896 bytes)
    float* conf_part = (float*)d_ws;                                        // 2688 * 4 = 10752
    unsigned long long* packed = (unsigned long long*)((char*)d_ws + 10752);// 384 * 8  =  3072
    float* ciou_ws = (float*)((char*)d_ws + 13824);                         // 384 * 4  =  1536
    int*   npos_ws = (int*)((char*)d_ws + 15360);                           // 384 * 4  =  1536

    hipLaunchKernelGGL(init_ws_k, dim3(1), dim3(512), 0, stream,
                       packed, ciou_ws, npos_ws);
    hipLaunchKernelGGL(level_k, dim3(N_BLK), dim3(256), 0, stream,
                       det8, det16, det32, gtb, conf_part, packed, ciou_ws, npos_ws);
    hipLaunchKernelGGL(fin_k, dim3(1), dim3(512), 0, stream,
                       q8, q16, q32, gtq, conf_part, packed, ciou_ws, npos_ws, out);
}

// Round 3
// 22.022 us; speedup vs baseline: 6.6945x; 1.6706x over previous
//
#include <hip/hip_runtime.h>
#include <math.h>

// ---------------------------------------------------------------------------
// StageALoss (FCOS-like): conf focal loss over all locations, CIoU over
// in-box locations, quality BCE at the argmin-dist location per (level,batch).
//
// R2 -> R3: (a) fast transcendentals (__expf/__logf/rcp) on the hot focal
// path (~3x fewer VALU instrs on 2.75M locations); (b) no atomics at all --
// per-block partial stores + static block->slot reduction in fin_k, which
// also removes the init kernel (2 launches instead of 3); (c) 8 locations
// per thread (2x float4 stripes) -> 1408 blocks, half the wave epilogues.
// ---------------------------------------------------------------------------

#define NBLK 1408   // lvl0: 1024 (8/batch), lvl1: 256 (2/batch), lvl2: 128 (1/batch)
#define N_PB 384    // 3 levels * 128 batches

__device__ __forceinline__ float rcpf(float x) { return __builtin_amdgcn_rcpf(x); }

__device__ __forceinline__ float logsigf(float x) {
    return fminf(x, 0.f) - log1pf(expf(-fabsf(x)));
}

// Process 4 consecutive-x locations starting at `loc` (16B-aligned).
__device__ __forceinline__ void proc4(
    const float* __restrict__ det, size_t c0base, int loc, int Wm1, int log2W,
    size_t HW, float stride, float x1, float y1, float x2, float y2,
    float bcx, float bcy,
    float& conf, float& ciou, int& np, unsigned long long& pk)
{
    const int xi = loc & Wm1;
    const int yi = loc >> log2W;
    const float cy = ((float)yi + 0.5f) * stride;

    float cxs[4]; bool inb[4]; bool anyb = false;
    #pragma unroll
    for (int j = 0; j < 4; ++j) {
        cxs[j] = ((float)(xi + j) + 0.5f) * stride;
        inb[j] = (cxs[j] > x1) & (cxs[j] < x2) & (cy > y1) & (cy < y2);
        anyb |= inb[j];
    }

    // channel 0: focal loss at every location (fast exp/log/rcp)
    const float4 d0 = *(const float4*)(det + c0base + (size_t)loc);
    const float zs[4] = { d0.x, d0.y, d0.z, d0.w };
    #pragma unroll
    for (int j = 0; j < 4; ++j) {
        const float z  = zs[j];
        const float e  = __expf(-fabsf(z));            // (0, 1]
        const float ce = fmaxf(z, 0.f) - (inb[j] ? z : 0.f) + __logf(1.f + e);
        const float inv = rcpf(1.f + e);
        const float p  = (z >= 0.f) ? inv : e * inv;   // sigmoid(z)
        const float pt = inb[j] ? p : 1.f - p;
        const float at = inb[j] ? 0.25f : 0.75f;
        const float om = 1.f - pt;
        conf += at * om * om * ce;
    }

    if (__any(anyb)) {  // wave-uniform: ltrb channels only near boxes
        const float4 d1 = *(const float4*)(det + c0base + HW + (size_t)loc);
        const float4 d2 = *(const float4*)(det + c0base + 2 * HW + (size_t)loc);
        const float4 d3 = *(const float4*)(det + c0base + 3 * HW + (size_t)loc);
        const float4 d4 = *(const float4*)(det + c0base + 4 * HW + (size_t)loc);
        const float ls[4] = { d1.x, d1.y, d1.z, d1.w };
        const float ts[4] = { d2.x, d2.y, d2.z, d2.w };
        const float rs[4] = { d3.x, d3.y, d3.z, d3.w };
        const float bs[4] = { d4.x, d4.y, d4.z, d4.w };
        #pragma unroll
        for (int j = 0; j < 4; ++j) {
            if (!inb[j]) continue;
            const float cx = cxs[j];
            const float pl  = __expf(fminf(fmaxf(ls[j], -6.f), 6.f)) * stride;
            const float pt_ = __expf(fminf(fmaxf(ts[j], -6.f), 6.f)) * stride;
            const float pr  = __expf(fminf(fmaxf(rs[j], -6.f), 6.f)) * stride;
            const float pb  = __expf(fminf(fmaxf(bs[j], -6.f), 6.f)) * stride;
            const float gl  = cx - x1, gtl = cy - y1, gr = x2 - cx, gb = y2 - cy;
            const float pw = pl + pr, ph = pt_ + pb;
            const float gw = gl + gr, gh = gtl + gb;
            const float iw = fmaxf(fminf(pl, gl) + fminf(pr, gr), 0.f);
            const float ih = fmaxf(fminf(pt_, gtl) + fminf(pb, gb), 0.f);
            const float inter = iw * ih;
            const float uni   = pw * ph + gw * gh - inter + 1e-6f;
            const float iou   = inter * rcpf(uni);
            const float cw_ = fmaxf(pl, gl) + fmaxf(pr, gr);
            const float ch_ = fmaxf(pt_, gtl) + fmaxf(pb, gb);
            const float c2  = cw_ * cw_ + ch_ * ch_ + 1e-6f;
            const float dcx = 0.5f * (pr - pl) - 0.5f * (gr - gl);
            const float dcy = 0.5f * (pb - pt_) - 0.5f * (gb - gtl);
            const float rho2 = dcx * dcx + dcy * dcy;
            const float dv = atanf(gw * rcpf(gh + 1e-6f)) - atanf(pw * rcpf(ph + 1e-6f));
            const float v  = (4.f / (float)(M_PI * M_PI)) * dv * dv;
            const float alpha = v * rcpf(1.f - iou + v + 1e-6f);
            ciou += 1.f - iou + rho2 * rcpf(c2) + alpha * v;
            ++np;
            const float ddx = cx - bcx, ddy = cy - bcy;
            const float dist2 = ddx * ddx + ddy * ddy;
            const unsigned long long cand =
                ((unsigned long long)__float_as_uint(dist2) << 32) | (unsigned)(loc + j);
            pk = cand < pk ? cand : pk;  // min -> first-index tie-break (argmin)
        }
    }
}

// Per-block partial stores, no atomics, no init kernel.
//   bid <  1024 : lvl0, b = bid>>3,        span = (bid&7)*2048, 2 vec-stripes
//   1024..1279  : lvl1, b = (bid-1024)>>1, span = (rel&1)*2048, 2 vec-stripes
//   1280..1407  : lvl2, b = bid-1280,      span = 0,            1 vec-stripe
__global__ __launch_bounds__(256) void level_k(
    const float* __restrict__ det8, const float* __restrict__ det16, const float* __restrict__ det32,
    const float* __restrict__ gtb,
    unsigned long long* __restrict__ pk_part, float* __restrict__ conf_part,
    float* __restrict__ ciou_part, int* __restrict__ np_part)
{
    const int bid = blockIdx.x;
    int b, base, log2W, nvec;
    const float* det; float stride; float inv_denom; size_t HW;
    if (bid < 1024) {
        b = bid >> 3; base = (bid & 7) * 2048; nvec = 2;
        det = det8;  stride = 8.f;  log2W = 7; HW = 16384; inv_denom = 1.f / 2097152.f;
    } else if (bid < 1280) {
        const int rel = bid - 1024;
        b = rel >> 1; base = (rel & 1) * 2048; nvec = 2;
        det = det16; stride = 16.f; log2W = 6; HW = 4096; inv_denom = 1.f / 524288.f;
    } else {
        b = bid - 1280; base = 0; nvec = 1;
        det = det32; stride = 32.f; log2W = 5; HW = 1024; inv_denom = 1.f / 131072.f;
    }

    const float x1 = gtb[b * 4 + 0];
    if (x1 < 0.f) {  // invalid batch contributes exactly 0 everywhere
        if (threadIdx.x == 0) {
            conf_part[bid] = 0.f; ciou_part[bid] = 0.f; np_part[bid] = 0;
            pk_part[bid] = ~0ULL;
        }
        return;
    }
    const float y1 = gtb[b * 4 + 1];
    const float x2 = gtb[b * 4 + 2];
    const float y2 = gtb[b * 4 + 3];
    const float bcx = 0.5f * (x1 + x2);
    const float bcy = 0.5f * (y1 + y2);

    const size_t c0base = (size_t)(b * 5) * HW;
    const int Wm1 = (1 << log2W) - 1;

    float conf = 0.f, ciou = 0.f; int np = 0;
    unsigned long long pk = ~0ULL;

    const int loc0 = base + ((int)threadIdx.x << 2);
    proc4(det, c0base, loc0, Wm1, log2W, HW, stride, x1, y1, x2, y2, bcx, bcy,
          conf, ciou, np, pk);
    if (nvec == 2)
        proc4(det, c0base, loc0 + 1024, Wm1, log2W, HW, stride, x1, y1, x2, y2, bcx, bcy,
              conf, ciou, np, pk);
    conf *= inv_denom;

    // wave (64-lane) shuffle reduction
    #pragma unroll
    for (int off = 32; off > 0; off >>= 1) {
        conf += __shfl_down(conf, off);
        ciou += __shfl_down(ciou, off);
        np   += __shfl_down(np, off);
        unsigned long long o = __shfl_down(pk, off);
        pk = o < pk ? o : pk;
    }

    // cross-wave via LDS, single store per block
    __shared__ float s_conf[4], s_ciou[4];
    __shared__ int   s_np[4];
    __shared__ unsigned long long s_pk[4];
    const int wid = threadIdx.x >> 6;
    if ((threadIdx.x & 63) == 0) {
        s_conf[wid] = conf; s_ciou[wid] = ciou; s_np[wid] = np; s_pk[wid] = pk;
    }
    __syncthreads();
    if (threadIdx.x == 0) {
        conf_part[bid] = s_conf[0] + s_conf[1] + s_conf[2] + s_conf[3];
        ciou_part[bid] = s_ciou[0] + s_ciou[1] + s_ciou[2] + s_ciou[3];
        np_part[bid]   = s_np[0] + s_np[1] + s_np[2] + s_np[3];
        unsigned long long mn = s_pk[0];
        mn = s_pk[1] < mn ? s_pk[1] : mn;
        mn = s_pk[2] < mn ? s_pk[2] : mn;
        mn = s_pk[3] < mn ? s_pk[3] : mn;
        pk_part[bid] = mn;
    }
}

__global__ __launch_bounds__(512) void fin_k(
    const float* __restrict__ q8, const float* __restrict__ q16, const float* __restrict__ q32,
    const float* __restrict__ gtq,
    const unsigned long long* __restrict__ pk_part, const float* __restrict__ conf_part,
    const float* __restrict__ ciou_part, const int* __restrict__ np_part,
    float* __restrict__ out)
{
    __shared__ float sc[512];
    __shared__ float sb[512];
    __shared__ float sq[512];
    __shared__ int   sn[512];
    const int i = threadIdx.x;

    float cp = 0.f;
    for (int j = i; j < NBLK; j += 512) cp += conf_part[j];

    float bb = 0.f, ql = 0.f; int n = 0;
    if (i < N_PB) {
        const int lvl = i >> 7, b = i & 127;
        // static block->slot mapping
        int first, cnt;
        if (lvl == 0)      { first = b * 8;        cnt = 8; }
        else if (lvl == 1) { first = 1024 + b * 2; cnt = 2; }
        else               { first = 1280 + b;     cnt = 1; }
        float ci = 0.f; int np = 0; unsigned long long mn = ~0ULL;
        for (int k = 0; k < cnt; ++k) {
            ci += ciou_part[first + k];
            np += np_part[first + k];
            const unsigned long long p = pk_part[first + k];
            mn = p < mn ? p : mn;
        }
        if (np > 0) {
            bb = ci / (float)np;  // ciou_mean
            const unsigned idx = (unsigned)(mn & 0xffffffffULL);
            const float* q; int log2HW;
            if (lvl == 0)      { q = q8;  log2HW = 14; }
            else if (lvl == 1) { q = q16; log2HW = 12; }
            else               { q = q32; log2HW = 10; }
            float s = 0.f;
            #pragma unroll
            for (int c = 0; c < 4; ++c) {
                const float best = q[((size_t)(b * 4 + c) << log2HW) + idx];
                const float qt = fminf(fmaxf(gtq[b * 4 + c], 0.05f), 0.95f);
                s -= qt * logsigf(best) + (1.f - qt) * logsigf(-best);
            }
            ql = 0.25f * s;  // bce.mean over C_Q=4
            n = 1;           // has_pos
        }
    }
    sc[i] = cp; sb[i] = bb; sq[i] = ql; sn[i] = n;
    __syncthreads();
    #pragma unroll
    for (int off = 256; off > 0; off >>= 1) {
        if (i < off) { sc[i] += sc[i + off]; sb[i] += sb[i + off]; sq[i] += sq[i + off]; sn[i] += sn[i + off]; }
        __syncthreads();
    }
    if (i == 0) {
        const float conf = sc[0];
        const int ntot = sn[0];
        const float denom = fmaxf((float)ntot, 1.f);
        const float tb = (ntot > 0) ? sb[0] / denom : sb[0];
        const float tq = (ntot > 0) ? sq[0] / denom : sq[0];
        out[0] = conf + 5.f * tb + 0.05f * tq;
        out[1] = conf;
        out[2] = tb;
        out[3] = tq;
    }
}

extern "C" void kernel_launch(void* const* d_in, const int* in_sizes, int n_in,
                              void* d_out, int out_size, void* d_ws, size_t ws_size,
                              hipStream_t stream) {
    const float* det8  = (const float*)d_in[0];
    const float* det16 = (const float*)d_in[1];
    const float* det32 = (const float*)d_in[2];
    const float* q8    = (const float*)d_in[3];
    const float* q16   = (const float*)d_in[4];
    const float* q32   = (const float*)d_in[5];
    const float* gtb   = (const float*)d_in[6];
    const float* gtq   = (const float*)d_in[7];
    float* out = (float*)d_out;

    // workspace layout (28160 bytes): u64 first for alignment
    unsigned long long* pk_part = (unsigned long long*)d_ws;        // 1408*8 = 11264
    float* conf_part = (float*)((char*)d_ws + 11264);               // 1408*4 =  5632
    float* ciou_part = (float*)((char*)d_ws + 16896);               // 1408*4 =  5632
    int*   np_part   = (int*)((char*)d_ws + 22528);                 // 1408*4 =  5632

    hipLaunchKernelGGL(level_k, dim3(NBLK), dim3(256), 0, stream,
                       det8, det16, det32, gtb, pk_part, conf_part, ciou_part, np_part);
    hipLaunchKernelGGL(fin_k, dim3(1), dim3(512), 0, stream,
                       q8, q16, q32, gtq, pk_part, conf_part, ciou_part, np_part, out);
}